// Round 9
// baseline (211.251 us; speedup 1.0000x reference)
//
#include <hip/hip_runtime.h>
#include <hip/hip_bf16.h>

#define B_SZ 8
#define SEQ 1024
#define DIM_ 1024
#define NH 16
#define HD 64
#define M_TOT (B_SZ*SEQ)   // 8192
#define N_QKV (3*DIM_)     // 3072

typedef __attribute__((ext_vector_type(8))) short bf16x8;
typedef __attribute__((ext_vector_type(4))) float f32x4;

typedef const __attribute__((address_space(1))) void gvoid;
typedef __attribute__((address_space(3))) void lvoid;

__device__ __forceinline__ short f2bf(float f){
  union { __hip_bfloat16 h; short s; } u;
  u.h = __float2bfloat16(f);
  return u.s;
}

// ---------------- kernel 1: fp32 -> bf16 elementwise ----------------
__global__ void cvt_kernel(const float* __restrict__ in, short* __restrict__ out, int n4){
  int i = blockIdx.x*blockDim.x + threadIdx.x;
  int stride = gridDim.x*blockDim.x;
  for (; i < n4; i += stride){
    float4 v = reinterpret_cast<const float4*>(in)[i];
    short4 s;
    s.x = f2bf(v.x); s.y = f2bf(v.y); s.z = f2bf(v.z); s.w = f2bf(v.w);
    reinterpret_cast<short4*>(out)[i] = s;
  }
}

// ------- kernel 2: transpose+convert fp32 [R][C] -> bf16 [C][R] -------
__global__ void tconv_kernel(const float* __restrict__ in, short* __restrict__ out, int R, int C){
  __shared__ alignas(16) short tile[64][66];
  const int l = threadIdx.x & 63, w = threadIdx.x >> 6;
  const int r0 = blockIdx.y * 64, c0 = blockIdx.x * 64;
  #pragma unroll
  for (int rr = 0; rr < 16; ++rr){
    int r = w + rr*4;
    tile[r][l] = f2bf(in[(size_t)(r0+r)*C + c0 + l]);
  }
  __syncthreads();
  #pragma unroll
  for (int cc = 0; cc < 16; ++cc){
    int c = w + cc*4;
    out[(size_t)(c0+c)*R + r0 + l] = tile[l][c];
  }
}

// ---- kernel 3: bf16 GEMM 256x128, BK=64, TRIPLE-buffered counted vmcnt ----
// The T4 lever (m218: counted vmcnt vs drain-0 = +38-73%): loads stay 2
// tiles deep in flight (12/thread); per-tile wait is vmcnt(12) -> the
// oldest batch (tile t) has landed, t+1/t+2 stay outstanding ACROSS the
// barriers. vmcnt(0) only at the last tile.
// Race-freedom: stage at iter t writes buf[(t+2)%3]; that buffer's last
// readers (tile t-1) all passed the end-barrier of iter t-1 before any
// wave enters iter t. Tile-t data-ready: vmcnt(12) + barrier before reads.
// 8 waves (2M x 4N), per-wave out 128x32, acc[8][2]. LDS 144 KiB.
// Swizzle: word ^= row&7 both sides (R3: measured 0 conflicts).
// EPI=0: scatter q/k/vT.  EPI=1: +bias, fp32 out.
template<int EPI, int GX>
__global__ __launch_bounds__(512, 2) void gemm6(
    const short* __restrict__ A, const short* __restrict__ Bt,
    int M, int Nn, int K,
    short* __restrict__ Qb, short* __restrict__ Kb, short* __restrict__ Vtb,
    const float* __restrict__ bias, float* __restrict__ outF)
{
  constexpr int BM = 256, BN = 128;
  __shared__ alignas(16) short As[3][BM*64];   // 3 x 32 KiB
  __shared__ alignas(16) short Bs[3][BN*64];   // 3 x 16 KiB

  // XCD-chunked remap: xcd = orig&7 owns 4 consecutive by rows x all bx
  const int orig = blockIdx.x;
  const int xcd = orig & 7, t0_ = orig >> 3;
  const int by = xcd*4 + t0_/GX, bx = t0_ % GX;

  const int tid = threadIdx.x;               // 0..511
  const int l = tid & 63, wid = tid >> 6;
  const int wr = wid >> 2, wc = wid & 3;     // 2M x 4N waves
  const int lr = l & 15, lw = l >> 4;
  const int sw8 = lr & 7;
  const int m0 = by * BM, n0 = bx * BN;

  f32x4 acc[8][2];
  const f32x4 zz = {0.f,0.f,0.f,0.f};
  #pragma unroll
  for (int m=0;m<8;m++){ acc[m][0] = zz; acc[m][1] = zz; }

  // staging: linear LDS dest, inverse-swizzled global source (G21)
  auto STAGE = [&](int q, int kt){
    const int k0 = kt << 6;
    #pragma unroll
    for (int j=0;j<4;j++){                    // A: 256x64 = 4 x 16B/thread
      const int idx = j*512 + tid;
      const int row = idx >> 3;
      const int ws  = (idx & 7) ^ (row & 7);
      __builtin_amdgcn_global_load_lds(
          (gvoid*)(A + (size_t)(m0+row)*K + k0 + ws*8),
          (lvoid*)(&As[q][idx*8]), 16, 0, 0);
    }
    #pragma unroll
    for (int j=0;j<2;j++){                    // B: 128x64 = 2 x 16B/thread
      const int idx = j*512 + tid;
      const int row = idx >> 3;
      const int ws  = (idx & 7) ^ (row & 7);
      __builtin_amdgcn_global_load_lds(
          (gvoid*)(Bt + (size_t)(n0+row)*K + k0 + ws*8),
          (lvoid*)(&Bs[q][idx*8]), 16, 0, 0);
    }
  };

  // prologue: 2 tiles in flight, confirm tile 0 landed (6 still out)
  STAGE(0, 0);
  STAGE(1, 1);
  asm volatile("s_waitcnt vmcnt(6)" ::: "memory");
  __builtin_amdgcn_sched_barrier(0);
  __builtin_amdgcn_s_barrier();
  __builtin_amdgcn_sched_barrier(0);

  const int NT = K >> 6;    // 16
  for (int t = 0; t < NT; ++t){
    const int cur = t % 3;
    if (t + 2 < NT) STAGE((t+2)%3, t+2);

    // wait: oldest in-flight batch (tile t) landed; newer stay outstanding
    if (t + 2 < NT)      asm volatile("s_waitcnt vmcnt(12)" ::: "memory");
    else if (t + 1 < NT) asm volatile("s_waitcnt vmcnt(6)"  ::: "memory");
    else                 asm volatile("s_waitcnt vmcnt(0)"  ::: "memory");
    __builtin_amdgcn_sched_barrier(0);
    __builtin_amdgcn_s_barrier();      // all waves: tile t fully in LDS
    __builtin_amdgcn_sched_barrier(0);

    bf16x8 af[2][8], bfr[2][2];
    #pragma unroll
    for (int ks=0;ks<2;ks++){
      const int wsel = ((lw + 4*ks) ^ sw8) << 3;
      #pragma unroll
      for (int m=0;m<8;m++){
        const int r = wr*128 + m*16 + lr;
        af[ks][m] = *(const bf16x8*)(&As[cur][r*64 + wsel]);
      }
      #pragma unroll
      for (int n=0;n<2;n++){
        const int r = wc*32 + n*16 + lr;
        bfr[ks][n] = *(const bf16x8*)(&Bs[cur][r*64 + wsel]);
      }
    }
    asm volatile("s_waitcnt lgkmcnt(0)" ::: "memory");
    __builtin_amdgcn_sched_barrier(0);

    __builtin_amdgcn_s_setprio(1);
    #pragma unroll
    for (int ks=0;ks<2;ks++)
      #pragma unroll
      for (int m=0;m<8;m++)
        #pragma unroll
        for (int n=0;n<2;n++)
          acc[m][n] = __builtin_amdgcn_mfma_f32_16x16x32_bf16(af[ks][m], bfr[ks][n], acc[m][n], 0, 0, 0);
    __builtin_amdgcn_s_setprio(0);

    __builtin_amdgcn_s_barrier();      // readers of buf[cur] done before
    __builtin_amdgcn_sched_barrier(0); // iter t+1 stages into buf[(t+3)%3==cur]
  }

  // epilogue
  #pragma unroll
  for (int n=0;n<2;n++){
    const int col = n0 + wc*32 + n*16 + lr;
    float bv = 0.f;
    if (EPI == 1) bv = bias[col];
    #pragma unroll
    for (int m=0;m<8;m++){
      const int rbase = m0 + wr*128 + m*16 + (lw<<2);
      #pragma unroll
      for (int ri=0;ri<4;ri++){
        const int row = rbase + ri;
        const float v = acc[m][n][ri];
        if (EPI == 0){
          const int three = col >> 10;
          const int cc = col & 1023;
          const int h = cc >> 6, d = cc & 63;
          const int b = row >> 10, nn = row & 1023;
          const int bh = b*NH + h;
          // Q pre-scaled by HD^-0.5 * log2(e) -> softmax in exp2 domain
          if (three == 0)      Qb[((size_t)bh*SEQ + nn)*HD + d] = f2bf(v * 0.1803368801f);
          else if (three == 1) Kb[((size_t)bh*SEQ + nn)*HD + d] = f2bf(v);
          else                 Vtb[((size_t)bh*HD + d)*SEQ + nn] = f2bf(v);
        } else {
          outF[(size_t)row*Nn + col] = v + bv;
        }
      }
    }
  }
}

// ---------------- kernel 4: flash attention (swapped QK^T) ----------------
// grid: B*H*(SEQ/64). block: 256 (4 waves x 16 q-rows). KVBLK=64, dbuf.
// K/V LDS: 64-word rows + XOR swizzle (word ^= row&7), both-sides involution.
__global__ __launch_bounds__(256) void attn_kernel(
    const short* __restrict__ Q, const short* __restrict__ Kb,
    const short* __restrict__ Vt, short* __restrict__ Ao)
{
  __shared__ alignas(16) short Ks[2][64*64];
  __shared__ alignas(16) short Vs[2][64*64];
  __shared__ alignas(16) short Ps[4][16*72];

  const int tid = threadIdx.x;
  const int l = tid & 63, w = tid >> 6;
  const int bid = blockIdx.x;
  const int qt = bid & 15, bh = bid >> 4;
  const int b = bh >> 4, h = bh & 15;
  const size_t base = (size_t)bh << 16;   // bh * SEQ * HD

  const int lr = l & 15;
  const int q4 = l >> 4;
  const int lk = q4 << 3;
  const int sw8 = lr & 7;

  // Q fragments (pre-scaled by HD^-0.5*log2e in QKV epilogue)
  const int qrow = qt*64 + w*16 + lr;
  const short* qp = Q + base + (size_t)qrow*HD + lk;
  const bf16x8 qf0 = *(const bf16x8*)qp;
  const bf16x8 qf1 = *(const bf16x8*)(qp + 32);

  float m_run = -1e30f, l_run = 0.f;
  f32x4 o[4];
  #pragma unroll
  for (int i=0;i<4;i++) o[i] = f32x4{0.f,0.f,0.f,0.f};

  bf16x8 kr[2], vr[2];
  auto load_tile = [&](int kt){
    const int kv0 = kt*64;
    #pragma unroll
    for (int p=0;p<2;p++){
      const int idx = tid + p*256;
      const int row = idx >> 3, c8 = (idx & 7) << 3;
      kr[p] = *(const bf16x8*)(Kb + base + (size_t)(kv0+row)*HD + c8);
      vr[p] = *(const bf16x8*)(Vt + base + (size_t)row*SEQ + kv0 + c8);
    }
  };
  auto write_tile = [&](int bi){
    #pragma unroll
    for (int p=0;p<2;p++){
      const int idx = tid + p*256;
      const int row = idx >> 3;
      const int wsw = ((idx & 7) ^ (row & 7)) << 3;   // swizzled word
      *(bf16x8*)(&Ks[bi][row*64 + wsw]) = kr[p];
      *(bf16x8*)(&Vs[bi][row*64 + wsw]) = vr[p];
    }
  };

  load_tile(0);
  write_tile(0);
  __syncthreads();

  int cur = 0;
  for (int kt = 0; kt < 16; ++kt){
    if (kt < 15) load_tile(kt+1);   // HBM loads overlap compute

    const short* kb = &Ks[cur][0];
    const short* vb = &Vs[cur][0];

    // S^T = K Q^T: lane holds S[k' = cg*16 + q4*4 + ri][q = lane&15]
    f32x4 s[4];
    #pragma unroll
    for (int cg=0;cg<4;cg++) s[cg] = f32x4{0.f,0.f,0.f,0.f};
    __builtin_amdgcn_s_setprio(1);
    #pragma unroll
    for (int cg=0;cg<4;cg++){
      const short* kp = kb + (cg*16 + lr)*64;
      bf16x8 kf0 = *(const bf16x8*)(kp + ((q4     ^ sw8) << 3));
      bf16x8 kf1 = *(const bf16x8*)(kp + (((q4+4) ^ sw8) << 3));
      s[cg] = __builtin_amdgcn_mfma_f32_16x16x32_bf16(kf0, qf0, s[cg], 0,0,0);
      s[cg] = __builtin_amdgcn_mfma_f32_16x16x32_bf16(kf1, qf1, s[cg], 0,0,0);
    }
    __builtin_amdgcn_s_setprio(0);

    // online softmax for this lane's q-row (exp2 domain)
    float mt = s[0][0];
    #pragma unroll
    for (int cg=0;cg<4;cg++)
      #pragma unroll
      for (int ri=0;ri<4;ri++) mt = fmaxf(mt, s[cg][ri]);
    mt = fmaxf(mt, __shfl_xor(mt, 16));
    mt = fmaxf(mt, __shfl_xor(mt, 32));

    const float mn = fmaxf(m_run, mt);
    const float corr = __builtin_amdgcn_exp2f(m_run - mn);
    m_run = mn;

    float p[4][4], rs = 0.f;
    #pragma unroll
    for (int cg=0;cg<4;cg++)
      #pragma unroll
      for (int ri=0;ri<4;ri++){
        p[cg][ri] = __builtin_amdgcn_exp2f(s[cg][ri] - mn);
        rs += p[cg][ri];
      }
    rs += __shfl_xor(rs, 16);
    rs += __shfl_xor(rs, 32);
    l_run = l_run*corr + rs;

    // P -> LDS as [q][k'] (wave-local buffer; wave-order LDS ops)
    short* pw = &Ps[w][0];
    #pragma unroll
    for (int cg=0;cg<4;cg++){
      short4 pk;
      pk.x = f2bf(p[cg][0]); pk.y = f2bf(p[cg][1]);
      pk.z = f2bf(p[cg][2]); pk.w = f2bf(p[cg][3]);
      *(short4*)(pw + lr*72 + cg*16 + q4*4) = pk;
    }

    // redistribute corr (per q=lane&15) to O rows (q = q4*4+ri)
    float corr_r[4];
    #pragma unroll
    for (int ri=0;ri<4;ri++) corr_r[ri] = __shfl(corr, (q4<<2) + ri);
    #pragma unroll
    for (int dg=0;dg<4;dg++)
      #pragma unroll
      for (int ri=0;ri<4;ri++) o[dg][ri] *= corr_r[ri];

    const bf16x8 pa0 = *(const bf16x8*)(pw + lr*72 + lk);
    const bf16x8 pa1 = *(const bf16x8*)(pw + lr*72 + lk + 32);
    __builtin_amdgcn_s_setprio(1);
    #pragma unroll
    for (int dg=0;dg<4;dg++){
      const short* vp = vb + (dg*16 + lr)*64;
      bf16x8 vf0 = *(const bf16x8*)(vp + ((q4     ^ sw8) << 3));
      bf16x8 vf1 = *(const bf16x8*)(vp + (((q4+4) ^ sw8) << 3));
      o[dg] = __builtin_amdgcn_mfma_f32_16x16x32_bf16(pa0, vf0, o[dg], 0,0,0);
      o[dg] = __builtin_amdgcn_mfma_f32_16x16x32_bf16(pa1, vf1, o[dg], 0,0,0);
    }
    __builtin_amdgcn_s_setprio(0);

    if (kt < 15) write_tile(cur ^ 1);
    __syncthreads();
    cur ^= 1;
  }

  // epilogue: O /= l, write bf16 [B*SEQ][DIM]
  float linv[4];
  #pragma unroll
  for (int ri=0;ri<4;ri++) linv[ri] = 1.0f / __shfl(l_run, (q4<<2) + ri);
  #pragma unroll
  for (int ri=0;ri<4;ri++){
    const int row = qt*64 + w*16 + (q4<<2) + ri;
    short* op = Ao + ((size_t)(b*SEQ + row))*DIM_ + h*HD;
    #pragma unroll
    for (int dg=0;dg<4;dg++)
      op[dg*16 + lr] = f2bf(o[dg][ri] * linv[ri]);
  }
}

// ---------------------------- launcher ----------------------------
extern "C" void kernel_launch(void* const* d_in, const int* in_sizes, int n_in,
                              void* d_out, int out_size, void* d_ws, size_t ws_size,
                              hipStream_t stream)
{
  (void)in_sizes; (void)n_in; (void)out_size; (void)ws_size;
  const float* x     = (const float*)d_in[0];
  const float* w_qkv = (const float*)d_in[1];
  const float* w_out = (const float*)d_in[2];
  const float* b_out = (const float*)d_in[3];
  float* out = (float*)d_out;

  char* ws = (char*)d_ws;
  const size_t MB = (size_t)1 << 20;
  short* xb    = (short*)(ws);            // 16 MiB  x bf16 [8192][1024]
  short* wqkvT = (short*)(ws + 16*MB);    //  6 MiB  w_qkv^T bf16 [3072][1024]
  short* woutT = (short*)(ws + 22*MB);    //  2 MiB  w_out^T bf16 [1024][1024]
  short* Qb    = (short*)(ws + 24*MB);    // 16 MiB  [bh][n][64] (pre-scaled)
  short* Kb    = (short*)(ws + 40*MB);    // 16 MiB  [bh][n][64]
  short* Vtb   = (short*)(ws + 56*MB);    // 16 MiB  [bh][64][n]
  short* Aob   = (short*)(ws + 72*MB);    // 16 MiB  attn out bf16 [8192][1024]

  cvt_kernel<<<2048, 256, 0, stream>>>(x, xb, (M_TOT*DIM_)/4);
  tconv_kernel<<<dim3(N_QKV/64, DIM_/64), 256, 0, stream>>>(w_qkv, wqkvT, DIM_, N_QKV);
  tconv_kernel<<<dim3(DIM_/64, DIM_/64), 256, 0, stream>>>(w_out, woutT, DIM_, DIM_);

  // QKV: 256x128 tiles, grid 32x24 = 768 blocks (XCD: 4 by-rows x 24 bx)
  gemm6<0,24><<<768, 512, 0, stream>>>(
      xb, wqkvT, M_TOT, N_QKV, DIM_, Qb, Kb, Vtb, nullptr, nullptr);

  attn_kernel<<<B_SZ*NH*(SEQ/64), 256, 0, stream>>>(Qb, Kb, Vtb, Aob);

  // OUT: 256x128 tiles, grid 32x8 = 256 blocks (XCD: 4 by-rows x 8 bx)
  gemm6<1,8><<<256, 512, 0, stream>>>(
      Aob, woutT, M_TOT, DIM_, DIM_, nullptr, nullptr, nullptr, b_out, out);
}

// Round 10
// 191.121 us; speedup vs baseline: 1.1053x; 1.1053x over previous
//
#include <hip/hip_runtime.h>
#include <hip/hip_bf16.h>

#define B_SZ 8
#define SEQ 1024
#define DIM_ 1024
#define NH 16
#define HD 64
#define M_TOT (B_SZ*SEQ)   // 8192
#define N_QKV (3*DIM_)     // 3072

typedef __attribute__((ext_vector_type(8))) short bf16x8;
typedef __attribute__((ext_vector_type(4))) float f32x4;

typedef const __attribute__((address_space(1))) void gvoid;
typedef __attribute__((address_space(3))) void lvoid;

__device__ __forceinline__ short f2bf(float f){
  union { __hip_bfloat16 h; short s; } u;
  u.h = __float2bfloat16(f);
  return u.s;
}

// ---------------- kernel 1: fp32 -> bf16 elementwise ----------------
__global__ void cvt_kernel(const float* __restrict__ in, short* __restrict__ out, int n4){
  int i = blockIdx.x*blockDim.x + threadIdx.x;
  int stride = gridDim.x*blockDim.x;
  for (; i < n4; i += stride){
    float4 v = reinterpret_cast<const float4*>(in)[i];
    short4 s;
    s.x = f2bf(v.x); s.y = f2bf(v.y); s.z = f2bf(v.z); s.w = f2bf(v.w);
    reinterpret_cast<short4*>(out)[i] = s;
  }
}

// ------- kernel 2: transpose+convert fp32 [R][C] -> bf16 [C][R] -------
__global__ void tconv_kernel(const float* __restrict__ in, short* __restrict__ out, int R, int C){
  __shared__ alignas(16) short tile[64][66];
  const int l = threadIdx.x & 63, w = threadIdx.x >> 6;
  const int r0 = blockIdx.y * 64, c0 = blockIdx.x * 64;
  #pragma unroll
  for (int rr = 0; rr < 16; ++rr){
    int r = w + rr*4;
    tile[r][l] = f2bf(in[(size_t)(r0+r)*C + c0 + l]);
  }
  __syncthreads();
  #pragma unroll
  for (int cc = 0; cc < 16; ++cc){
    int c = w + cc*4;
    out[(size_t)(c0+c)*R + r0 + l] = tile[l][c];
  }
}

// ---- kernel 3: bf16 GEMM 128x128, BK=32, 4 waves, dbuf, 4 blocks/CU ----
// R8 structure (best so far). This round: (1) QKV split into QK-dispatch
// (NOFF=0, row-friendly stores) and V-dispatch (NOFF=16, scatter) with
// IDENTICAL inner loops -> rocprof separates their dur_us = in-harness
// ablation of the scatter epilogue. (2) V scatter packed as short4 (nn
// consecutive over ri). (3) setprio REMOVED from gemm (m190: negative on
// this structure).
// EPI=0: scatter q/k/vT.  EPI=1: +bias, fp32 out.
template<int EPI, int GX, int NOFF>
__global__ __launch_bounds__(256, 4) void gemm5(
    const short* __restrict__ A, const short* __restrict__ Bt,
    int M, int Nn, int K,
    short* __restrict__ Qb, short* __restrict__ Kb, short* __restrict__ Vtb,
    const float* __restrict__ bias, float* __restrict__ outF)
{
  __shared__ alignas(16) short As[2][128*32];   // 2 x 8 KiB
  __shared__ alignas(16) short Bs[2][128*32];   // 2 x 8 KiB  (32 KiB total)

  // XCD-chunked remap: xcd = id&7 gets 8 consecutive by rows x all bx
  const int orig = blockIdx.x;
  const int xcd = orig & 7, t = orig >> 3;
  const int by = xcd*8 + t/GX, bx = t % GX;

  const int tid = threadIdx.x;               // 0..255
  const int l = tid & 63, wid = tid >> 6;
  const int wr = wid >> 1, wc = wid & 1;     // 2M x 2N waves, 64x64 each
  const int lr = l & 15, lw = l >> 4;
  const int sw = (lr >> 1) & 3;              // swizzle key ((row>>1)&3)
  const int m0 = by * 128, n0 = (bx + NOFF) * 128;

  f32x4 acc[4][4];
  const f32x4 zz = {0.f,0.f,0.f,0.f};
  #pragma unroll
  for (int m=0;m<4;m++)
    #pragma unroll
    for (int n=0;n<4;n++) acc[m][n] = zz;

  // staging: linear LDS dest, inverse-swizzled global source.
  auto STAGE = [&](int buf, int kt){
    const int k0 = kt << 5;
    #pragma unroll
    for (int j=0;j<2;j++){
      const int idx = j*256 + tid;     // 0..511
      const int row = idx >> 2;        // 0..127
      const int ws  = (idx & 3) ^ ((row >> 1) & 3);
      __builtin_amdgcn_global_load_lds(
          (gvoid*)(A + (size_t)(m0+row)*K + k0 + ws*8),
          (lvoid*)(&As[buf][idx*8]), 16, 0, 0);
    }
    #pragma unroll
    for (int j=0;j<2;j++){
      const int idx = j*256 + tid;
      const int row = idx >> 2;
      const int ws  = (idx & 3) ^ ((row >> 1) & 3);
      __builtin_amdgcn_global_load_lds(
          (gvoid*)(Bt + (size_t)(n0+row)*K + k0 + ws*8),
          (lvoid*)(&Bs[buf][idx*8]), 16, 0, 0);
    }
  };

  STAGE(0, 0);
  __syncthreads();

  const int NT = K >> 5;    // 32 K-tiles
  int buf = 0;
  for (int kt = 0; kt < NT; ++kt){
    if (kt + 1 < NT) STAGE(buf ^ 1, kt + 1);   // issue next-tile loads FIRST

    bf16x8 af[4], bfr[4];
    const int wsel = (lw ^ sw) << 3;
    #pragma unroll
    for (int m=0;m<4;m++){
      const int r = wr*64 + m*16 + lr;
      af[m] = *(const bf16x8*)(&As[buf][r*32 + wsel]);
    }
    #pragma unroll
    for (int n=0;n<4;n++){
      const int r = wc*64 + n*16 + lr;
      bfr[n] = *(const bf16x8*)(&Bs[buf][r*32 + wsel]);
    }
    #pragma unroll
    for (int m=0;m<4;m++)
      #pragma unroll
      for (int n=0;n<4;n++)
        acc[m][n] = __builtin_amdgcn_mfma_f32_16x16x32_bf16(af[m], bfr[n], acc[m][n], 0, 0, 0);

    __syncthreads();
    buf ^= 1;
  }

  // epilogue
  #pragma unroll
  for (int n=0;n<4;n++){
    const int col = n0 + wc*64 + n*16 + lr;
    if (EPI == 0){
      const int three = col >> 10;
      const int cc = col & 1023;
      const int h = cc >> 6, d = cc & 63;
      #pragma unroll
      for (int m=0;m<4;m++){
        const int rbase = m0 + wr*64 + m*16 + (lw<<2);
        const int b = rbase >> 10, nn = rbase & 1023;
        const int bh = b*NH + h;
        if (three == 2){
          // V^T: nn consecutive over ri -> one 8B packed store
          short4 pk;
          pk.x = f2bf(acc[m][n][0]); pk.y = f2bf(acc[m][n][1]);
          pk.z = f2bf(acc[m][n][2]); pk.w = f2bf(acc[m][n][3]);
          *(short4*)(&Vtb[((size_t)bh*HD + d)*SEQ + nn]) = pk;
        } else if (three == 0){
          #pragma unroll
          for (int ri=0;ri<4;ri++)
            Qb[((size_t)bh*SEQ + nn + ri)*HD + d] = f2bf(acc[m][n][ri] * 0.1803368801f);
        } else {
          #pragma unroll
          for (int ri=0;ri<4;ri++)
            Kb[((size_t)bh*SEQ + nn + ri)*HD + d] = f2bf(acc[m][n][ri]);
        }
      }
    } else {
      const float bv = bias[col];
      #pragma unroll
      for (int m=0;m<4;m++){
        const int rbase = m0 + wr*64 + m*16 + (lw<<2);
        #pragma unroll
        for (int ri=0;ri<4;ri++)
          outF[(size_t)(rbase+ri)*Nn + col] = acc[m][n][ri] + bv;
      }
    }
  }
}

// ---------------- kernel 4: flash attention (swapped QK^T) ----------------
// grid: B*H*(SEQ/64). block: 256 (4 waves x 16 q-rows). KVBLK=64, dbuf.
// K/V LDS: 64-word rows + XOR swizzle (word ^= row&7), both-sides involution.
__global__ __launch_bounds__(256) void attn_kernel(
    const short* __restrict__ Q, const short* __restrict__ Kb,
    const short* __restrict__ Vt, short* __restrict__ Ao)
{
  __shared__ alignas(16) short Ks[2][64*64];
  __shared__ alignas(16) short Vs[2][64*64];
  __shared__ alignas(16) short Ps[4][16*72];

  const int tid = threadIdx.x;
  const int l = tid & 63, w = tid >> 6;
  const int bid = blockIdx.x;
  const int qt = bid & 15, bh = bid >> 4;
  const int b = bh >> 4, h = bh & 15;
  const size_t base = (size_t)bh << 16;   // bh * SEQ * HD

  const int lr = l & 15;
  const int q4 = l >> 4;
  const int lk = q4 << 3;
  const int sw8 = lr & 7;

  // Q fragments (pre-scaled by HD^-0.5*log2e in QKV epilogue)
  const int qrow = qt*64 + w*16 + lr;
  const short* qp = Q + base + (size_t)qrow*HD + lk;
  const bf16x8 qf0 = *(const bf16x8*)qp;
  const bf16x8 qf1 = *(const bf16x8*)(qp + 32);

  float m_run = -1e30f, l_run = 0.f;
  f32x4 o[4];
  #pragma unroll
  for (int i=0;i<4;i++) o[i] = f32x4{0.f,0.f,0.f,0.f};

  bf16x8 kr[2], vr[2];
  auto load_tile = [&](int kt){
    const int kv0 = kt*64;
    #pragma unroll
    for (int p=0;p<2;p++){
      const int idx = tid + p*256;
      const int row = idx >> 3, c8 = (idx & 7) << 3;
      kr[p] = *(const bf16x8*)(Kb + base + (size_t)(kv0+row)*HD + c8);
      vr[p] = *(const bf16x8*)(Vt + base + (size_t)row*SEQ + kv0 + c8);
    }
  };
  auto write_tile = [&](int bi){
    #pragma unroll
    for (int p=0;p<2;p++){
      const int idx = tid + p*256;
      const int row = idx >> 3;
      const int wsw = ((idx & 7) ^ (row & 7)) << 3;   // swizzled word
      *(bf16x8*)(&Ks[bi][row*64 + wsw]) = kr[p];
      *(bf16x8*)(&Vs[bi][row*64 + wsw]) = vr[p];
    }
  };

  load_tile(0);
  write_tile(0);
  __syncthreads();

  int cur = 0;
  for (int kt = 0; kt < 16; ++kt){
    if (kt < 15) load_tile(kt+1);   // HBM loads overlap compute

    const short* kb = &Ks[cur][0];
    const short* vb = &Vs[cur][0];

    // S^T = K Q^T: lane holds S[k' = cg*16 + q4*4 + ri][q = lane&15]
    f32x4 s[4];
    #pragma unroll
    for (int cg=0;cg<4;cg++) s[cg] = f32x4{0.f,0.f,0.f,0.f};
    __builtin_amdgcn_s_setprio(1);
    #pragma unroll
    for (int cg=0;cg<4;cg++){
      const short* kp = kb + (cg*16 + lr)*64;
      bf16x8 kf0 = *(const bf16x8*)(kp + ((q4     ^ sw8) << 3));
      bf16x8 kf1 = *(const bf16x8*)(kp + (((q4+4) ^ sw8) << 3));
      s[cg] = __builtin_amdgcn_mfma_f32_16x16x32_bf16(kf0, qf0, s[cg], 0,0,0);
      s[cg] = __builtin_amdgcn_mfma_f32_16x16x32_bf16(kf1, qf1, s[cg], 0,0,0);
    }
    __builtin_amdgcn_s_setprio(0);

    // online softmax for this lane's q-row (exp2 domain)
    float mt = s[0][0];
    #pragma unroll
    for (int cg=0;cg<4;cg++)
      #pragma unroll
      for (int ri=0;ri<4;ri++) mt = fmaxf(mt, s[cg][ri]);
    mt = fmaxf(mt, __shfl_xor(mt, 16));
    mt = fmaxf(mt, __shfl_xor(mt, 32));

    const float mn = fmaxf(m_run, mt);
    const float corr = __builtin_amdgcn_exp2f(m_run - mn);
    m_run = mn;

    float p[4][4], rs = 0.f;
    #pragma unroll
    for (int cg=0;cg<4;cg++)
      #pragma unroll
      for (int ri=0;ri<4;ri++){
        p[cg][ri] = __builtin_amdgcn_exp2f(s[cg][ri] - mn);
        rs += p[cg][ri];
      }
    rs += __shfl_xor(rs, 16);
    rs += __shfl_xor(rs, 32);
    l_run = l_run*corr + rs;

    // P -> LDS as [q][k'] (wave-local buffer; wave-order LDS ops)
    short* pw = &Ps[w][0];
    #pragma unroll
    for (int cg=0;cg<4;cg++){
      short4 pk;
      pk.x = f2bf(p[cg][0]); pk.y = f2bf(p[cg][1]);
      pk.z = f2bf(p[cg][2]); pk.w = f2bf(p[cg][3]);
      *(short4*)(pw + lr*72 + cg*16 + q4*4) = pk;
    }

    // redistribute corr (per q=lane&15) to O rows (q = q4*4+ri)
    float corr_r[4];
    #pragma unroll
    for (int ri=0;ri<4;ri++) corr_r[ri] = __shfl(corr, (q4<<2) + ri);
    #pragma unroll
    for (int dg=0;dg<4;dg++)
      #pragma unroll
      for (int ri=0;ri<4;ri++) o[dg][ri] *= corr_r[ri];

    const bf16x8 pa0 = *(const bf16x8*)(pw + lr*72 + lk);
    const bf16x8 pa1 = *(const bf16x8*)(pw + lr*72 + lk + 32);
    __builtin_amdgcn_s_setprio(1);
    #pragma unroll
    for (int dg=0;dg<4;dg++){
      const short* vp = vb + (dg*16 + lr)*64;
      bf16x8 vf0 = *(const bf16x8*)(vp + ((q4     ^ sw8) << 3));
      bf16x8 vf1 = *(const bf16x8*)(vp + (((q4+4) ^ sw8) << 3));
      o[dg] = __builtin_amdgcn_mfma_f32_16x16x32_bf16(pa0, vf0, o[dg], 0,0,0);
      o[dg] = __builtin_amdgcn_mfma_f32_16x16x32_bf16(pa1, vf1, o[dg], 0,0,0);
    }
    __builtin_amdgcn_s_setprio(0);

    if (kt < 15) write_tile(cur ^ 1);
    __syncthreads();
    cur ^= 1;
  }

  // epilogue: O /= l, write bf16 [B*SEQ][DIM]
  float linv[4];
  #pragma unroll
  for (int ri=0;ri<4;ri++) linv[ri] = 1.0f / __shfl(l_run, (q4<<2) + ri);
  #pragma unroll
  for (int ri=0;ri<4;ri++){
    const int row = qt*64 + w*16 + (q4<<2) + ri;
    short* op = Ao + ((size_t)(b*SEQ + row))*DIM_ + h*HD;
    #pragma unroll
    for (int dg=0;dg<4;dg++)
      op[dg*16 + lr] = f2bf(o[dg][ri] * linv[ri]);
  }
}

// ---------------------------- launcher ----------------------------
extern "C" void kernel_launch(void* const* d_in, const int* in_sizes, int n_in,
                              void* d_out, int out_size, void* d_ws, size_t ws_size,
                              hipStream_t stream)
{
  (void)in_sizes; (void)n_in; (void)out_size; (void)ws_size;
  const float* x     = (const float*)d_in[0];
  const float* w_qkv = (const float*)d_in[1];
  const float* w_out = (const float*)d_in[2];
  const float* b_out = (const float*)d_in[3];
  float* out = (float*)d_out;

  char* ws = (char*)d_ws;
  const size_t MB = (size_t)1 << 20;
  short* xb    = (short*)(ws);            // 16 MiB  x bf16 [8192][1024]
  short* wqkvT = (short*)(ws + 16*MB);    //  6 MiB  w_qkv^T bf16 [3072][1024]
  short* woutT = (short*)(ws + 22*MB);    //  2 MiB  w_out^T bf16 [1024][1024]
  short* Qb    = (short*)(ws + 24*MB);    // 16 MiB  [bh][n][64] (pre-scaled)
  short* Kb    = (short*)(ws + 40*MB);    // 16 MiB  [bh][n][64]
  short* Vtb   = (short*)(ws + 56*MB);    // 16 MiB  [bh][64][n]
  short* Aob   = (short*)(ws + 72*MB);    // 16 MiB  attn out bf16 [8192][1024]

  cvt_kernel<<<2048, 256, 0, stream>>>(x, xb, (M_TOT*DIM_)/4);
  tconv_kernel<<<dim3(N_QKV/64, DIM_/64), 256, 0, stream>>>(w_qkv, wqkvT, DIM_, N_QKV);
  tconv_kernel<<<dim3(DIM_/64, DIM_/64), 256, 0, stream>>>(w_out, woutT, DIM_, DIM_);

  // QK-dispatch: cols 0-2047, 64 by x 16 bx = 1024 blocks (XCD: 8 by x 16)
  gemm5<0,16,0><<<1024, 256, 0, stream>>>(
      xb, wqkvT, M_TOT, N_QKV, DIM_, Qb, Kb, Vtb, nullptr, nullptr);

  // V-dispatch: cols 2048-3071, 64 by x 8 bx = 512 blocks (XCD: 8 by x 8)
  gemm5<0,8,16><<<512, 256, 0, stream>>>(
      xb, wqkvT, M_TOT, N_QKV, DIM_, Qb, Kb, Vtb, nullptr, nullptr);

  attn_kernel<<<B_SZ*NH*(SEQ/64), 256, 0, stream>>>(Qb, Kb, Vtb, Aob);

  // OUT: 128x128 tiles, grid 64x8 = 512 blocks (XCD chunk: 8 by-rows x 8)
  gemm5<1,8,0><<<512, 256, 0, stream>>>(
      Aob, woutT, M_TOT, DIM_, DIM_, nullptr, nullptr, nullptr, b_out, out);
}

// Round 11
// 184.517 us; speedup vs baseline: 1.1449x; 1.0358x over previous
//
#include <hip/hip_runtime.h>
#include <hip/hip_bf16.h>

#define B_SZ 8
#define SEQ 1024
#define DIM_ 1024
#define NH 16
#define HD 64
#define M_TOT (B_SZ*SEQ)   // 8192
#define N_QKV (3*DIM_)     // 3072

typedef __attribute__((ext_vector_type(8))) short bf16x8;
typedef __attribute__((ext_vector_type(4))) float f32x4;

typedef const __attribute__((address_space(1))) void gvoid;
typedef __attribute__((address_space(3))) void lvoid;

__device__ __forceinline__ short f2bf(float f){
  union { __hip_bfloat16 h; short s; } u;
  u.h = __float2bfloat16(f);
  return u.s;
}

// ---------------- kernel 1: fp32 -> bf16 elementwise ----------------
__global__ void cvt_kernel(const float* __restrict__ in, short* __restrict__ out, int n4){
  int i = blockIdx.x*blockDim.x + threadIdx.x;
  int stride = gridDim.x*blockDim.x;
  for (; i < n4; i += stride){
    float4 v = reinterpret_cast<const float4*>(in)[i];
    short4 s;
    s.x = f2bf(v.x); s.y = f2bf(v.y); s.z = f2bf(v.z); s.w = f2bf(v.w);
    reinterpret_cast<short4*>(out)[i] = s;
  }
}

// ------- kernel 2: transpose+convert fp32 [R][C] -> bf16 [C][R] -------
__global__ void tconv_kernel(const float* __restrict__ in, short* __restrict__ out, int R, int C){
  __shared__ alignas(16) short tile[64][66];
  const int l = threadIdx.x & 63, w = threadIdx.x >> 6;
  const int r0 = blockIdx.y * 64, c0 = blockIdx.x * 64;
  #pragma unroll
  for (int rr = 0; rr < 16; ++rr){
    int r = w + rr*4;
    tile[r][l] = f2bf(in[(size_t)(r0+r)*C + c0 + l]);
  }
  __syncthreads();
  #pragma unroll
  for (int cc = 0; cc < 16; ++cc){
    int c = w + cc*4;
    out[(size_t)(c0+c)*R + r0 + l] = tile[l][c];
  }
}

// ---- kernel 3: bf16 GEMM 128x128, BK=32, 4 waves, dbuf (R10, unchanged) ----
// EPI=0: scatter q/k/vT (packed V stores).  EPI=1: +bias, fp32 out.
template<int EPI, int GX, int NOFF>
__global__ __launch_bounds__(256, 4) void gemm5(
    const short* __restrict__ A, const short* __restrict__ Bt,
    int M, int Nn, int K,
    short* __restrict__ Qb, short* __restrict__ Kb, short* __restrict__ Vtb,
    const float* __restrict__ bias, float* __restrict__ outF)
{
  __shared__ alignas(16) short As[2][128*32];   // 2 x 8 KiB
  __shared__ alignas(16) short Bs[2][128*32];   // 2 x 8 KiB  (32 KiB total)

  const int orig = blockIdx.x;
  const int xcd = orig & 7, t = orig >> 3;
  const int by = xcd*8 + t/GX, bx = t % GX;

  const int tid = threadIdx.x;               // 0..255
  const int l = tid & 63, wid = tid >> 6;
  const int wr = wid >> 1, wc = wid & 1;     // 2M x 2N waves, 64x64 each
  const int lr = l & 15, lw = l >> 4;
  const int sw = (lr >> 1) & 3;              // swizzle key ((row>>1)&3)
  const int m0 = by * 128, n0 = (bx + NOFF) * 128;

  f32x4 acc[4][4];
  const f32x4 zz = {0.f,0.f,0.f,0.f};
  #pragma unroll
  for (int m=0;m<4;m++)
    #pragma unroll
    for (int n=0;n<4;n++) acc[m][n] = zz;

  auto STAGE = [&](int buf, int kt){
    const int k0 = kt << 5;
    #pragma unroll
    for (int j=0;j<2;j++){
      const int idx = j*256 + tid;     // 0..511
      const int row = idx >> 2;        // 0..127
      const int ws  = (idx & 3) ^ ((row >> 1) & 3);
      __builtin_amdgcn_global_load_lds(
          (gvoid*)(A + (size_t)(m0+row)*K + k0 + ws*8),
          (lvoid*)(&As[buf][idx*8]), 16, 0, 0);
    }
    #pragma unroll
    for (int j=0;j<2;j++){
      const int idx = j*256 + tid;
      const int row = idx >> 2;
      const int ws  = (idx & 3) ^ ((row >> 1) & 3);
      __builtin_amdgcn_global_load_lds(
          (gvoid*)(Bt + (size_t)(n0+row)*K + k0 + ws*8),
          (lvoid*)(&Bs[buf][idx*8]), 16, 0, 0);
    }
  };

  STAGE(0, 0);
  __syncthreads();

  const int NT = K >> 5;    // 32 K-tiles
  int buf = 0;
  for (int kt = 0; kt < NT; ++kt){
    if (kt + 1 < NT) STAGE(buf ^ 1, kt + 1);   // issue next-tile loads FIRST

    bf16x8 af[4], bfr[4];
    const int wsel = (lw ^ sw) << 3;
    #pragma unroll
    for (int m=0;m<4;m++){
      const int r = wr*64 + m*16 + lr;
      af[m] = *(const bf16x8*)(&As[buf][r*32 + wsel]);
    }
    #pragma unroll
    for (int n=0;n<4;n++){
      const int r = wc*64 + n*16 + lr;
      bfr[n] = *(const bf16x8*)(&Bs[buf][r*32 + wsel]);
    }
    #pragma unroll
    for (int m=0;m<4;m++)
      #pragma unroll
      for (int n=0;n<4;n++)
        acc[m][n] = __builtin_amdgcn_mfma_f32_16x16x32_bf16(af[m], bfr[n], acc[m][n], 0, 0, 0);

    __syncthreads();
    buf ^= 1;
  }

  // epilogue
  #pragma unroll
  for (int n=0;n<4;n++){
    const int col = n0 + wc*64 + n*16 + lr;
    if (EPI == 0){
      const int three = col >> 10;
      const int cc = col & 1023;
      const int h = cc >> 6, d = cc & 63;
      #pragma unroll
      for (int m=0;m<4;m++){
        const int rbase = m0 + wr*64 + m*16 + (lw<<2);
        const int b = rbase >> 10, nn = rbase & 1023;
        const int bh = b*NH + h;
        if (three == 2){
          short4 pk;
          pk.x = f2bf(acc[m][n][0]); pk.y = f2bf(acc[m][n][1]);
          pk.z = f2bf(acc[m][n][2]); pk.w = f2bf(acc[m][n][3]);
          *(short4*)(&Vtb[((size_t)bh*HD + d)*SEQ + nn]) = pk;
        } else if (three == 0){
          #pragma unroll
          for (int ri=0;ri<4;ri++)
            Qb[((size_t)bh*SEQ + nn + ri)*HD + d] = f2bf(acc[m][n][ri] * 0.1803368801f);
        } else {
          #pragma unroll
          for (int ri=0;ri<4;ri++)
            Kb[((size_t)bh*SEQ + nn + ri)*HD + d] = f2bf(acc[m][n][ri]);
        }
      }
    } else {
      const float bv = bias[col];
      #pragma unroll
      for (int m=0;m<4;m++){
        const int rbase = m0 + wr*64 + m*16 + (lw<<2);
        #pragma unroll
        for (int ri=0;ri<4;ri++)
          outF[(size_t)(rbase+ri)*Nn + col] = acc[m][n][ri] + bv;
      }
    }
  }
}

// ---------------- kernel 4: flash attention v2 ----------------
// 1024 blocks = 128 bh x 8 q-tiles(128 rows). 4 waves x 32 q-rows (2 frag
// groups A/B per wave) -> K/V LDS reads amortized 2x. K/V staged via
// global_load_lds DMA (pre-swizzled source). bh-affine XCD remap: all 8
// q-tiles of a head on one XCD -> K/V L2-resident.
__global__ __launch_bounds__(256) void attn_kernel(
    const short* __restrict__ Q, const short* __restrict__ Kb,
    const short* __restrict__ Vt, short* __restrict__ Ao)
{
  __shared__ alignas(16) short Ks[2][64*64];
  __shared__ alignas(16) short Vs[2][64*64];
  __shared__ alignas(16) short Ps[4][32*72];

  const int tid = threadIdx.x;
  const int l = tid & 63, w = tid >> 6;
  // XCD remap: xcd = orig&7; bh = g*8+xcd (bh&7 == xcd)
  const int orig = blockIdx.x;
  const int xcd = orig & 7, n_ = orig >> 3;
  const int g = n_ >> 3, qt = n_ & 7;
  const int bh = g*8 + xcd;
  const int b = bh >> 4, h = bh & 15;
  const size_t base = (size_t)bh << 16;   // bh * SEQ * HD

  const int lr = l & 15;
  const int q4 = l >> 4;
  const int lk = q4 << 3;
  const int sw8 = lr & 7;

  // Q fragments for both 16-row groups (pre-scaled by HD^-0.5*log2e)
  const int qrowA = qt*128 + w*32 + lr;
  const short* qpA = Q + base + (size_t)qrowA*HD + lk;
  const bf16x8 qfA0 = *(const bf16x8*)qpA;
  const bf16x8 qfA1 = *(const bf16x8*)(qpA + 32);
  const short* qpB = qpA + 16*HD;
  const bf16x8 qfB0 = *(const bf16x8*)qpB;
  const bf16x8 qfB1 = *(const bf16x8*)(qpB + 32);

  float mA = -1e30f, lA = 0.f, mB = -1e30f, lB = 0.f;
  f32x4 oA[4], oB[4];
  #pragma unroll
  for (int i=0;i<4;i++){ oA[i] = f32x4{0.f,0.f,0.f,0.f}; oB[i] = f32x4{0.f,0.f,0.f,0.f}; }

  // DMA staging: linear LDS dest, inverse-swizzled global source (G21)
  auto STAGE = [&](int bi, int kt){
    const int kv0 = kt*64;
    #pragma unroll
    for (int j=0;j<2;j++){
      const int idx = j*256 + tid;
      const int row = idx >> 3;                    // 0..63
      const int wsw = (idx & 7) ^ (row & 7);
      __builtin_amdgcn_global_load_lds(
          (gvoid*)(Kb + base + (size_t)(kv0+row)*HD + wsw*8),
          (lvoid*)(&Ks[bi][idx*8]), 16, 0, 0);
      __builtin_amdgcn_global_load_lds(
          (gvoid*)(Vt + base + (size_t)row*SEQ + kv0 + wsw*8),
          (lvoid*)(&Vs[bi][idx*8]), 16, 0, 0);
    }
  };

  STAGE(0, 0);
  __syncthreads();

  int cur = 0;
  for (int kt = 0; kt < 16; ++kt){
    if (kt < 15) STAGE(cur ^ 1, kt+1);   // DMA overlaps compute

    const short* kb = &Ks[cur][0];
    const short* vb = &Vs[cur][0];

    // S^T = K Q^T for both groups; K frags read ONCE, feed 2 MFMAs each
    f32x4 sA[4], sB[4];
    #pragma unroll
    for (int cg=0;cg<4;cg++){ sA[cg] = f32x4{0.f,0.f,0.f,0.f}; sB[cg] = f32x4{0.f,0.f,0.f,0.f}; }
    __builtin_amdgcn_s_setprio(1);
    #pragma unroll
    for (int cg=0;cg<4;cg++){
      const short* kp = kb + (cg*16 + lr)*64;
      bf16x8 kf0 = *(const bf16x8*)(kp + ((q4     ^ sw8) << 3));
      bf16x8 kf1 = *(const bf16x8*)(kp + (((q4+4) ^ sw8) << 3));
      sA[cg] = __builtin_amdgcn_mfma_f32_16x16x32_bf16(kf0, qfA0, sA[cg], 0,0,0);
      sA[cg] = __builtin_amdgcn_mfma_f32_16x16x32_bf16(kf1, qfA1, sA[cg], 0,0,0);
      sB[cg] = __builtin_amdgcn_mfma_f32_16x16x32_bf16(kf0, qfB0, sB[cg], 0,0,0);
      sB[cg] = __builtin_amdgcn_mfma_f32_16x16x32_bf16(kf1, qfB1, sB[cg], 0,0,0);
    }
    __builtin_amdgcn_s_setprio(0);

    short* pw = &Ps[w][0];

    // ---- softmax group A (exp2 domain), pack P immediately ----
    {
      float mt = sA[0][0];
      #pragma unroll
      for (int cg=0;cg<4;cg++)
        #pragma unroll
        for (int ri=0;ri<4;ri++) mt = fmaxf(mt, sA[cg][ri]);
      mt = fmaxf(mt, __shfl_xor(mt, 16));
      mt = fmaxf(mt, __shfl_xor(mt, 32));
      const float mn = fmaxf(mA, mt);
      const float corr = __builtin_amdgcn_exp2f(mA - mn);
      mA = mn;
      float rs = 0.f;
      #pragma unroll
      for (int cg=0;cg<4;cg++){
        float p0 = __builtin_amdgcn_exp2f(sA[cg][0] - mn);
        float p1 = __builtin_amdgcn_exp2f(sA[cg][1] - mn);
        float p2 = __builtin_amdgcn_exp2f(sA[cg][2] - mn);
        float p3 = __builtin_amdgcn_exp2f(sA[cg][3] - mn);
        rs += (p0+p1)+(p2+p3);
        short4 pk; pk.x=f2bf(p0); pk.y=f2bf(p1); pk.z=f2bf(p2); pk.w=f2bf(p3);
        *(short4*)(pw + lr*72 + cg*16 + q4*4) = pk;
      }
      rs += __shfl_xor(rs, 16);
      rs += __shfl_xor(rs, 32);
      lA = lA*corr + rs;
      float corr_r[4];
      #pragma unroll
      for (int ri=0;ri<4;ri++) corr_r[ri] = __shfl(corr, (q4<<2) + ri);
      #pragma unroll
      for (int dg=0;dg<4;dg++)
        #pragma unroll
        for (int ri=0;ri<4;ri++) oA[dg][ri] *= corr_r[ri];
    }
    // ---- softmax group B ----
    {
      float mt = sB[0][0];
      #pragma unroll
      for (int cg=0;cg<4;cg++)
        #pragma unroll
        for (int ri=0;ri<4;ri++) mt = fmaxf(mt, sB[cg][ri]);
      mt = fmaxf(mt, __shfl_xor(mt, 16));
      mt = fmaxf(mt, __shfl_xor(mt, 32));
      const float mn = fmaxf(mB, mt);
      const float corr = __builtin_amdgcn_exp2f(mB - mn);
      mB = mn;
      float rs = 0.f;
      #pragma unroll
      for (int cg=0;cg<4;cg++){
        float p0 = __builtin_amdgcn_exp2f(sB[cg][0] - mn);
        float p1 = __builtin_amdgcn_exp2f(sB[cg][1] - mn);
        float p2 = __builtin_amdgcn_exp2f(sB[cg][2] - mn);
        float p3 = __builtin_amdgcn_exp2f(sB[cg][3] - mn);
        rs += (p0+p1)+(p2+p3);
        short4 pk; pk.x=f2bf(p0); pk.y=f2bf(p1); pk.z=f2bf(p2); pk.w=f2bf(p3);
        *(short4*)(pw + (16+lr)*72 + cg*16 + q4*4) = pk;
      }
      rs += __shfl_xor(rs, 16);
      rs += __shfl_xor(rs, 32);
      lB = lB*corr + rs;
      float corr_r[4];
      #pragma unroll
      for (int ri=0;ri<4;ri++) corr_r[ri] = __shfl(corr, (q4<<2) + ri);
      #pragma unroll
      for (int dg=0;dg<4;dg++)
        #pragma unroll
        for (int ri=0;ri<4;ri++) oB[dg][ri] *= corr_r[ri];
    }

    // P fragments (wave-local LDS; lgkmcnt orders write->read)
    const bf16x8 paA0 = *(const bf16x8*)(pw + lr*72 + lk);
    const bf16x8 paA1 = *(const bf16x8*)(pw + lr*72 + lk + 32);
    const bf16x8 paB0 = *(const bf16x8*)(pw + (16+lr)*72 + lk);
    const bf16x8 paB1 = *(const bf16x8*)(pw + (16+lr)*72 + lk + 32);

    __builtin_amdgcn_s_setprio(1);
    #pragma unroll
    for (int dg=0;dg<4;dg++){
      const short* vp = vb + (dg*16 + lr)*64;
      bf16x8 vf0 = *(const bf16x8*)(vp + ((q4     ^ sw8) << 3));
      bf16x8 vf1 = *(const bf16x8*)(vp + (((q4+4) ^ sw8) << 3));
      oA[dg] = __builtin_amdgcn_mfma_f32_16x16x32_bf16(paA0, vf0, oA[dg], 0,0,0);
      oA[dg] = __builtin_amdgcn_mfma_f32_16x16x32_bf16(paA1, vf1, oA[dg], 0,0,0);
      oB[dg] = __builtin_amdgcn_mfma_f32_16x16x32_bf16(paB0, vf0, oB[dg], 0,0,0);
      oB[dg] = __builtin_amdgcn_mfma_f32_16x16x32_bf16(paB1, vf1, oB[dg], 0,0,0);
    }
    __builtin_amdgcn_s_setprio(0);

    __syncthreads();   // DMA for next tile landed; buf readers done
    cur ^= 1;
  }

  // epilogue: O /= l, write bf16 [B*SEQ][DIM]
  float linvA[4], linvB[4];
  #pragma unroll
  for (int ri=0;ri<4;ri++){
    linvA[ri] = 1.0f / __shfl(lA, (q4<<2) + ri);
    linvB[ri] = 1.0f / __shfl(lB, (q4<<2) + ri);
  }
  #pragma unroll
  for (int ri=0;ri<4;ri++){
    const int rowA = qt*128 + w*32 + (q4<<2) + ri;
    short* opA = Ao + ((size_t)(b*SEQ + rowA))*DIM_ + h*HD;
    short* opB = opA + 16*DIM_;
    #pragma unroll
    for (int dg=0;dg<4;dg++){
      opA[dg*16 + lr] = f2bf(oA[dg][ri] * linvA[ri]);
      opB[dg*16 + lr] = f2bf(oB[dg][ri] * linvB[ri]);
    }
  }
}

// ---------------------------- launcher ----------------------------
extern "C" void kernel_launch(void* const* d_in, const int* in_sizes, int n_in,
                              void* d_out, int out_size, void* d_ws, size_t ws_size,
                              hipStream_t stream)
{
  (void)in_sizes; (void)n_in; (void)out_size; (void)ws_size;
  const float* x     = (const float*)d_in[0];
  const float* w_qkv = (const float*)d_in[1];
  const float* w_out = (const float*)d_in[2];
  const float* b_out = (const float*)d_in[3];
  float* out = (float*)d_out;

  char* ws = (char*)d_ws;
  const size_t MB = (size_t)1 << 20;
  short* xb    = (short*)(ws);            // 16 MiB  x bf16 [8192][1024]
  short* wqkvT = (short*)(ws + 16*MB);    //  6 MiB  w_qkv^T bf16 [3072][1024]
  short* woutT = (short*)(ws + 22*MB);    //  2 MiB  w_out^T bf16 [1024][1024]
  short* Qb    = (short*)(ws + 24*MB);    // 16 MiB  [bh][n][64] (pre-scaled)
  short* Kb    = (short*)(ws + 40*MB);    // 16 MiB  [bh][n][64]
  short* Vtb   = (short*)(ws + 56*MB);    // 16 MiB  [bh][64][n]
  short* Aob   = (short*)(ws + 72*MB);    // 16 MiB  attn out bf16 [8192][1024]

  cvt_kernel<<<2048, 256, 0, stream>>>(x, xb, (M_TOT*DIM_)/4);
  tconv_kernel<<<dim3(N_QKV/64, DIM_/64), 256, 0, stream>>>(w_qkv, wqkvT, DIM_, N_QKV);
  tconv_kernel<<<dim3(DIM_/64, DIM_/64), 256, 0, stream>>>(w_out, woutT, DIM_, DIM_);

  // QK-dispatch: cols 0-2047, 64 by x 16 bx = 1024 blocks
  gemm5<0,16,0><<<1024, 256, 0, stream>>>(
      xb, wqkvT, M_TOT, N_QKV, DIM_, Qb, Kb, Vtb, nullptr, nullptr);

  // V-dispatch: cols 2048-3071, 64 by x 8 bx = 512 blocks
  gemm5<0,8,16><<<512, 256, 0, stream>>>(
      xb, wqkvT, M_TOT, N_QKV, DIM_, Qb, Kb, Vtb, nullptr, nullptr);

  // attn: 128 bh x 8 q-tiles(128) = 1024 blocks
  attn_kernel<<<1024, 256, 0, stream>>>(Qb, Kb, Vtb, Aob);

  // OUT: 128x128 tiles, grid 64x8 = 512 blocks
  gemm5<1,8,0><<<512, 256, 0, stream>>>(
      Aob, woutT, M_TOT, DIM_, DIM_, nullptr, nullptr, nullptr, b_out, out);
}